// Round 6
// baseline (1551.960 us; speedup 1.0000x reference)
//
#include <hip/hip_runtime.h>
#include <hip/hip_bf16.h>

#define B_TOT 65536

// Pure-VALU fp32 reference-mirror kernel. 32 rows per block, 256 threads.
// Inputs float32, outputs FLOAT32 (fp32 words; idx stored as float value).
// LDS: A_ = xs[32][160] -> h2[32][256] -> psum[32][64][4]
//      Bb = h1[32][256] -> feat[32][128] | dist[32][64] @4096 | idx @6144
__global__ __launch_bounds__(256) void udp_kernel(
    const float* __restrict__ obs, const float* __restrict__ act,
    const float* __restrict__ obs2, const float* __restrict__ rew,
    const float* __restrict__ W0, const float* __restrict__ b0,
    const float* __restrict__ W1, const float* __restrict__ b1,
    const float* __restrict__ W2, const float* __restrict__ b2,
    const float* __restrict__ Wp, const float* __restrict__ emb,
    const float* __restrict__ sigma, float* __restrict__ out) {
  __shared__ __align__(16) float A_[8192];
  __shared__ __align__(16) float Bb[8192];
  const int t = threadIdx.x;
  const int blockRow = blockIdx.x * 32;

  float* out0 = out;                        // chosen_embedding (B,32)
  float* out1 = out + (size_t)B_TOT * 32;   // chosen_dist (B,1)
  float* out2 = out + (size_t)B_TOT * 33;   // idx (B,1) as float
  float* out3 = out + (size_t)B_TOT * 34;   // chosen_mean (B,32)
  float* out4 = out + (size_t)B_TOT * 66;   // distance (B,64)

  // ---- S1: stage x = [obs | obs2-obs | act | rew] fp32 into A_ ----
  for (int i = t; i < 32 * 160; i += 256) {
    int r = i / 160, k = i - r * 160;
    int row = blockRow + r;
    float v;
    if (k < 64)        v = obs[row * 64 + k];
    else if (k < 128)  v = obs2[row * 64 + (k - 64)] - obs[row * 64 + (k - 64)];
    else if (k < 144)  v = act[row * 16 + (k - 128)];
    else if (k == 144) v = rew[row];
    else               v = 0.f;
    A_[i] = v;
  }
  __syncthreads();

  // ---- S2: layer 0 (145 -> 256). thread = neuron t; 32 rows in regs ----
  {
    float acc[32];
#pragma unroll
    for (int r = 0; r < 32; ++r) acc[r] = 0.f;
    for (int k4 = 0; k4 < 144; k4 += 4) {
      float w0v = W0[(k4 + 0) * 256 + t];
      float w1v = W0[(k4 + 1) * 256 + t];
      float w2v = W0[(k4 + 2) * 256 + t];
      float w3v = W0[(k4 + 3) * 256 + t];
#pragma unroll
      for (int r = 0; r < 32; ++r) {
        const float4 xv = *(const float4*)&A_[r * 160 + k4];  // LDS broadcast
        acc[r] = fmaf(xv.x, w0v, acc[r]);
        acc[r] = fmaf(xv.y, w1v, acc[r]);
        acc[r] = fmaf(xv.z, w2v, acc[r]);
        acc[r] = fmaf(xv.w, w3v, acc[r]);
      }
    }
    {
      float wv = W0[144 * 256 + t];
#pragma unroll
      for (int r = 0; r < 32; ++r) acc[r] = fmaf(A_[r * 160 + 144], wv, acc[r]);
    }
    float bb = b0[t];
#pragma unroll
    for (int r = 0; r < 32; ++r) {
      float v = acc[r] + bb;
      v = v > 0.f ? v : 0.01f * v;
      Bb[r * 256 + t] = v;  // h1
    }
  }
  __syncthreads();

  // ---- S3: layer 1 (256 -> 256) ----
  {
    float acc[32];
#pragma unroll
    for (int r = 0; r < 32; ++r) acc[r] = 0.f;
    for (int k4 = 0; k4 < 256; k4 += 4) {
      float w0v = W1[(k4 + 0) * 256 + t];
      float w1v = W1[(k4 + 1) * 256 + t];
      float w2v = W1[(k4 + 2) * 256 + t];
      float w3v = W1[(k4 + 3) * 256 + t];
#pragma unroll
      for (int r = 0; r < 32; ++r) {
        const float4 hv = *(const float4*)&Bb[r * 256 + k4];  // broadcast
        acc[r] = fmaf(hv.x, w0v, acc[r]);
        acc[r] = fmaf(hv.y, w1v, acc[r]);
        acc[r] = fmaf(hv.z, w2v, acc[r]);
        acc[r] = fmaf(hv.w, w3v, acc[r]);
      }
    }
    float bb = b1[t];
    // A_ (xs) fully consumed before the post-S2 barrier -> safe to overwrite
#pragma unroll
    for (int r = 0; r < 32; ++r) {
      float v = acc[r] + bb;
      v = v > 0.f ? v : 0.01f * v;
      A_[r * 256 + t] = v;  // h2
    }
  }
  __syncthreads();

  // ---- S4: layer 2 (256 -> 128). thread = (neuron t&127, row-half t>>7) ----
  {
    const int n = t & 127, half = t >> 7;  // half uniform per wave
    float acc[16];
#pragma unroll
    for (int r = 0; r < 16; ++r) acc[r] = 0.f;
    for (int k4 = 0; k4 < 256; k4 += 4) {
      float w0v = W2[(k4 + 0) * 128 + n];
      float w1v = W2[(k4 + 1) * 128 + n];
      float w2v = W2[(k4 + 2) * 128 + n];
      float w3v = W2[(k4 + 3) * 128 + n];
#pragma unroll
      for (int r = 0; r < 16; ++r) {
        const float4 hv = *(const float4*)&A_[(half * 16 + r) * 256 + k4];
        acc[r] = fmaf(hv.x, w0v, acc[r]);
        acc[r] = fmaf(hv.y, w1v, acc[r]);
        acc[r] = fmaf(hv.z, w2v, acc[r]);
        acc[r] = fmaf(hv.w, w3v, acc[r]);
      }
    }
    float bb = b2[n];
#pragma unroll
    for (int r = 0; r < 16; ++r) {
      float v = acc[r] + bb;
      v = v > 0.f ? v : 0.01f * v;
      Bb[(half * 16 + r) * 128 + n] = v;  // feat in Bb[0..4095]
    }
  }
  __syncthreads();

  // ---- S5: projection + diff^2 partials (numpy pairwise tree) ----
  // thread = (env n = t&63, partial p = t>>6 wave-uniform). numpy's 8
  // accumulators r_j (j = e mod 8, m ascending); this thread owns
  // j in {2p, 2p+1}, writes s_p = r_{2p} + r_{2p+1};
  // final (s0+s1)+(s2+s3) == numpy's pairwise tree for n=32.
  {
    const int n = t & 63, pp = t >> 6;
    float rj[2][32];
#pragma unroll
    for (int jj = 0; jj < 2; ++jj)
#pragma unroll
      for (int r = 0; r < 32; ++r) rj[jj][r] = 0.f;
#pragma unroll
    for (int jj = 0; jj < 2; ++jj) {
      for (int m = 0; m < 4; ++m) {
        int e = 2 * pp + jj + 8 * m;
        const float* wrow = Wp + (n * 32 + e) * 128;
        float em = emb[n * 32 + e];
        float acc[32];
#pragma unroll
        for (int r = 0; r < 32; ++r) acc[r] = 0.f;
        for (int f4 = 0; f4 < 128; f4 += 4) {
          const float4 wv = *(const float4*)(wrow + f4);
#pragma unroll
          for (int r = 0; r < 32; ++r) {
            const float4 fv = *(const float4*)&Bb[r * 128 + f4];  // broadcast
            acc[r] = fmaf(fv.x, wv.x, acc[r]);
            acc[r] = fmaf(fv.y, wv.y, acc[r]);
            acc[r] = fmaf(fv.z, wv.z, acc[r]);
            acc[r] = fmaf(fv.w, wv.w, acc[r]);
          }
        }
#pragma unroll
        for (int r = 0; r < 32; ++r) {
          float d = acc[r] - em;
          rj[jj][r] = fmaf(d, d, rj[jj][r]);
        }
      }
    }
#pragma unroll
    for (int r = 0; r < 32; ++r)
      A_[r * 256 + n * 4 + pp] = rj[0][r] + rj[1][r];  // psum (A_ dead post-S4)
  }
  __syncthreads();

  // ---- S6: distance + argmin per row (threads 0..31) ----
  if (t < 32) {
    const int r = t, row = blockRow + r;
    float best = 1e30f;
    int bi = 0;
    for (int n = 0; n < 64; ++n) {
      const float* ps = &A_[r * 256 + n * 4];
      float s = (ps[0] + ps[1]) + (ps[2] + ps[3]);  // numpy pairwise combine
      float mean = s / 32.0f;                        // exact (pow2)
      float sg = sigma[n];
      float den = 2.0f * sg * sg;                    // np: (2.0*s)*s
      float dist = expf((-mean) / den);
      Bb[4096 + r * 64 + n] = dist;
      if (dist < best) { best = dist; bi = n; }      // np.argmin first-min
    }
    Bb[6144 + r] = (float)bi;
    out1[row] = best;
    out2[row] = (float)bi;
  }
  __syncthreads();

  // ---- S7a: distance matrix out ----
  for (int i = t; i < 32 * 64; i += 256) {
    int r = i >> 6, n = i & 63;
    out4[(size_t)(blockRow + r) * 64 + n] = Bb[4096 + i];
  }
  // ---- S7b: chosen embedding (recompute f2e[idx]) + chosen mean ----
  for (int i = t; i < 32 * 32; i += 256) {
    int r = i >> 5, e = i & 31;
    int bi = (int)Bb[6144 + r];
    const float* wrow = Wp + (bi * 32 + e) * 128;
    float acc = 0.f;
    for (int f4 = 0; f4 < 128; f4 += 4) {
      const float4 wv = *(const float4*)(wrow + f4);
      const float4 fv = *(const float4*)&Bb[r * 128 + f4];
      acc = fmaf(fv.x, wv.x, acc);
      acc = fmaf(fv.y, wv.y, acc);
      acc = fmaf(fv.z, wv.z, acc);
      acc = fmaf(fv.w, wv.w, acc);
    }
    size_t row = (size_t)blockRow + r;
    out0[row * 32 + e] = acc;
    out3[row * 32 + e] = emb[bi * 32 + e];
  }
}

extern "C" void kernel_launch(void* const* d_in, const int* in_sizes, int n_in,
                              void* d_out, int out_size, void* d_ws, size_t ws_size,
                              hipStream_t stream) {
  const float* obs   = (const float*)d_in[0];
  const float* act   = (const float*)d_in[1];
  const float* obs2  = (const float*)d_in[2];
  const float* rew   = (const float*)d_in[3];
  const float* W0    = (const float*)d_in[4];
  const float* b0    = (const float*)d_in[5];
  const float* W1    = (const float*)d_in[6];
  const float* b1    = (const float*)d_in[7];
  const float* W2    = (const float*)d_in[8];
  const float* b2    = (const float*)d_in[9];
  const float* Wp    = (const float*)d_in[10];
  const float* e_emb = (const float*)d_in[11];
  const float* sigma = (const float*)d_in[12];

  udp_kernel<<<dim3(B_TOT / 32), dim3(256), 0, stream>>>(
      obs, act, obs2, rew, W0, b0, W1, b1, W2, b2, Wp, e_emb, sigma,
      (float*)d_out);
}